// Round 18
// baseline (398.183 us; speedup 1.0000x reference)
//
#include <hip/hip_runtime.h>
#include <hip/hip_bf16.h>
#include <stdint.h>

#define SLEN 2048
#define HIDN 4096
#define NHEAD 32
#define NKV 8
#define HD 128
#define QKV_N 6144

typedef __hip_bfloat16 bf16;
typedef short short8 __attribute__((ext_vector_type(8)));
typedef _Float16 f16x8 __attribute__((ext_vector_type(8)));
typedef float f32x4 __attribute__((ext_vector_type(4)));
typedef float f32x16 __attribute__((ext_vector_type(16)));

__device__ __forceinline__ void gld16(const void* g, void* l) {
  __builtin_amdgcn_global_load_lds((const __attribute__((address_space(1))) void*)g,
                                   (__attribute__((address_space(3))) void*)l,
                                   16, 0, 0);
}

// packed bf16 convert: lo16 = bf16(a), hi16 = bf16(b)  [T12 recipe]
__device__ __forceinline__ unsigned int cvtpk(float a, float b) {
  unsigned int r;
  asm("v_cvt_pk_bf16_f32 %0, %1, %2" : "=v"(r) : "v"(a), "v"(b));
  return r;
}

// Pipelined bf16 GEMM (round-12 proven): C[M,N](fp32) = A[M,K] * B[N,K]^T.
__global__ __launch_bounds__(256, 2) void gemm_pipe_kernel(
    const bf16* __restrict__ A, const bf16* __restrict__ B,
    float* __restrict__ C, int K, int lda, int ldb, int ldc)
{
  __shared__ __align__(16) bf16 sA[2][128 * 64];
  __shared__ __align__(16) bf16 sB[2][128 * 64];

  const int bidlin = blockIdx.y * gridDim.x + blockIdx.x;
  const int xcd = bidlin & 7;
  const int local = bidlin >> 3;
  const int CW = gridDim.x >> 2;
  const int cx = xcd & 3, cy = xcd >> 2;
  const int bx = cx * CW + local % CW;
  const int by = cy * (gridDim.y >> 1) + local / CW;
  const int row0 = by * 128;
  const int col0 = bx * 128;

  const int tid = threadIdx.x;
  const int w = tid >> 6;
  const int lane = tid & 63;
  const int wr = w >> 1, wc = w & 1;
  const int fr = lane & 15;
  const int g = lane >> 4;

  auto stage = [&](int t, int b) {
    const int k0 = t << 6;
#pragma unroll
    for (int i = 0; i < 4; ++i) {
      const int c = i * 256 + tid;
      const int row = c >> 3;
      const int slot = (c & 7) ^ (row & 7);
      gld16(A + (long)(row0 + row) * lda + k0 + slot * 8,
            (bf16*)sA[b] + (i * 256 + w * 64) * 8);
    }
#pragma unroll
    for (int i = 0; i < 4; ++i) {
      const int c = i * 256 + tid;
      const int row = c >> 3;
      const int slot = (c & 7) ^ (row & 7);
      gld16(B + (long)(col0 + row) * ldb + k0 + slot * 8,
            (bf16*)sB[b] + (i * 256 + w * 64) * 8);
    }
  };

  f32x4 acc[4][4] = {};
  const int nk = K >> 6;

  stage(0, 0);

  for (int t = 0; t < nk; ++t) {
    const int buf = t & 1;
    __builtin_amdgcn_s_barrier();
    __builtin_amdgcn_sched_barrier(0);
    if (t + 1 < nk) {
      stage(t + 1, buf ^ 1);
      asm volatile("s_waitcnt vmcnt(8)" ::: "memory");
    } else {
      asm volatile("s_waitcnt vmcnt(0)" ::: "memory");
    }
    __builtin_amdgcn_sched_barrier(0);
    __builtin_amdgcn_s_barrier();
    __builtin_amdgcn_sched_barrier(0);

    const bf16* Ab = sA[buf];
    const bf16* Bb = sB[buf];

    short8 afr[4][2], bfr[4][2];
#pragma unroll
    for (int mf = 0; mf < 4; ++mf)
#pragma unroll
      for (int ks = 0; ks < 2; ++ks) {
        const int ra = wr * 64 + mf * 16 + fr;
        afr[mf][ks] = *(const short8*)(Ab + ra * 64 + (((ks << 2) + g) ^ (ra & 7)) * 8);
        const int rb = wc * 64 + mf * 16 + fr;
        bfr[mf][ks] = *(const short8*)(Bb + rb * 64 + (((ks << 2) + g) ^ (rb & 7)) * 8);
      }
    __builtin_amdgcn_s_setprio(1);
#pragma unroll
    for (int mf = 0; mf < 4; ++mf)
#pragma unroll
      for (int nf = 0; nf < 4; ++nf)
#pragma unroll
        for (int ks = 0; ks < 2; ++ks)
          acc[mf][nf] = __builtin_amdgcn_mfma_f32_16x16x32_bf16(
              afr[mf][ks], bfr[nf][ks], acc[mf][nf], 0, 0, 0);
    __builtin_amdgcn_s_setprio(0);
  }

  const int cr = g << 2;
#pragma unroll
  for (int mf = 0; mf < 4; ++mf)
#pragma unroll
    for (int nf = 0; nf < 4; ++nf)
#pragma unroll
      for (int r = 0; r < 4; ++r) {
        const long row = row0 + wr * 64 + mf * 16 + cr + r;
        const long col = col0 + wc * 64 + nf * 16 + fr;
        C[row * (long)ldc + col] = acc[mf][nf][r];
      }
}

// QKV GEMM, v2: BK=32 main loop (32 KB LDS) + slim epilogue (bf16 RoPE-partner
// tile, register-exact RMSNorm) -> 35 KB total -> 3 blocks/CU, 768 = 3x256
// grid = 100% fill. Per-block tile [128 s][128 d] is one head.
__global__ __launch_bounds__(256, 3) void gemm_qkv_kernel(
    const bf16* __restrict__ A, const bf16* __restrict__ B,
    _Float16* __restrict__ qf, _Float16* __restrict__ kf,
    bf16* __restrict__ Vt,
    const float* __restrict__ cosb, const float* __restrict__ sinb,
    const float* __restrict__ qw, const float* __restrict__ kw,
    const float* __restrict__ epsp, int K, int lda, int ldb)
{
  __shared__ __align__(16) char smem[35840];
  bf16* sAb = (bf16*)smem;                   // [2][128*32] = 16 KB
  bf16* sBb = (bf16*)(smem + 16384);         // [2][128*32] = 16 KB
  unsigned short* T16 = (unsigned short*)smem;  // epi: [128][136] 2B = 34816
  float* stat = (float*)(smem + 34816);      // [128][2] = 1 KB

  const int bidlin = blockIdx.y * gridDim.x + blockIdx.x;
  const int xcd = bidlin & 7;
  const int local = bidlin >> 3;
  const int CW = gridDim.x >> 2;
  const int cx = xcd & 3, cy = xcd >> 2;
  const int bx = cx * CW + local % CW;
  const int by = cy * (gridDim.y >> 1) + local / CW;
  const int row0 = by * 128;
  const int col0 = bx * 128;

  const int tid = threadIdx.x;
  const int w = tid >> 6;
  const int lane = tid & 63;
  const int wr = w >> 1, wc = w & 1;
  const int fr = lane & 15;
  const int g = lane >> 4;

  auto stage = [&](int t, int b) {
    const int k0 = t << 5;
#pragma unroll
    for (int i = 0; i < 2; ++i) {
      const int c = i * 256 + tid;
      const int row = c >> 2;
      const int slot = (c & 3) ^ (row & 3);
      gld16(A + (long)(row0 + row) * lda + k0 + slot * 8,
            sAb + b * 4096 + (i * 256 + w * 64) * 8);
    }
#pragma unroll
    for (int i = 0; i < 2; ++i) {
      const int c = i * 256 + tid;
      const int row = c >> 2;
      const int slot = (c & 3) ^ (row & 3);
      gld16(B + (long)(col0 + row) * ldb + k0 + slot * 8,
            sBb + b * 4096 + (i * 256 + w * 64) * 8);
    }
  };

  f32x4 acc[4][4] = {};
  const int nk = K >> 5;   // 128 tiles of BK=32

  stage(0, 0);

  for (int t = 0; t < nk; ++t) {
    const int buf = t & 1;
    __builtin_amdgcn_s_barrier();
    __builtin_amdgcn_sched_barrier(0);
    if (t + 1 < nk) {
      stage(t + 1, buf ^ 1);
      asm volatile("s_waitcnt vmcnt(4)" ::: "memory");
    } else {
      asm volatile("s_waitcnt vmcnt(0)" ::: "memory");
    }
    __builtin_amdgcn_sched_barrier(0);
    __builtin_amdgcn_s_barrier();
    __builtin_amdgcn_sched_barrier(0);

    const bf16* Ab = sAb + buf * 4096;
    const bf16* Bb = sBb + buf * 4096;

    short8 afr[4], bfr[4];
#pragma unroll
    for (int mf = 0; mf < 4; ++mf) {
      const int ra = wr * 64 + mf * 16 + fr;
      afr[mf] = *(const short8*)(Ab + ra * 32 + (g ^ (ra & 3)) * 8);
      const int rb = wc * 64 + mf * 16 + fr;
      bfr[mf] = *(const short8*)(Bb + rb * 32 + (g ^ (rb & 3)) * 8);
    }
    __builtin_amdgcn_s_setprio(1);
#pragma unroll
    for (int mf = 0; mf < 4; ++mf)
#pragma unroll
      for (int nf = 0; nf < 4; ++nf)
        acc[mf][nf] = __builtin_amdgcn_mfma_f32_16x16x32_bf16(
            afr[mf], bfr[nf], acc[mf][nf], 0, 0, 0);
    __builtin_amdgcn_s_setprio(0);
  }

  // ---- slim fused epilogue ----
  __syncthreads();                 // all LDS reads done; smem reusable
  const int slot = col0 >> 7;      // 0..31 Q heads, 32..39 K, 40..47 V
  const int cr = g << 2;

  if (slot < 40) {
    // 1) exact fp32 row-ssq: in-register + fr-shuffles + cross-wc stat
    float ssqp[4][4];
#pragma unroll
    for (int mf = 0; mf < 4; ++mf)
#pragma unroll
      for (int r = 0; r < 4; ++r) {
        float s = 0.0f;
#pragma unroll
        for (int nf = 0; nf < 4; ++nf) s += acc[mf][nf][r] * acc[mf][nf][r];
        s += __shfl_xor(s, 1);
        s += __shfl_xor(s, 2);
        s += __shfl_xor(s, 4);
        s += __shfl_xor(s, 8);
        ssqp[mf][r] = s;
      }
    if (fr == 0) {
#pragma unroll
      for (int mf = 0; mf < 4; ++mf)
#pragma unroll
        for (int r = 0; r < 4; ++r)
          stat[(wr * 64 + mf * 16 + cr + r) * 2 + wc] = ssqp[mf][r];
    }
    __syncthreads();

    const float epsv = epsp[0];
    const float scale = (slot < 32) ? 1.4426950408889634f : 1.0f;
    const float* nw = (slot < 32) ? qw : kw;
    float nwv[4];
#pragma unroll
    for (int nf = 0; nf < 4; ++nf) nwv[nf] = nw[wc * 64 + nf * 16 + fr];

    float rrv[4][4];
#pragma unroll
    for (int mf = 0; mf < 4; ++mf)
#pragma unroll
      for (int r = 0; r < 4; ++r) {
        const int row = wr * 64 + mf * 16 + cr + r;
        rrv[mf][r] = rsqrtf((stat[row * 2] + stat[row * 2 + 1]) * (1.0f / 128.0f) + epsv);
      }

    // 2) normalized values -> bf16 T16 (RoPE partner exchange)
    float nv[4][4][4];
#pragma unroll
    for (int mf = 0; mf < 4; ++mf)
#pragma unroll
      for (int nf = 0; nf < 4; ++nf)
#pragma unroll
        for (int r = 0; r < 4; ++r) {
          const float v = acc[mf][nf][r] * rrv[mf][r] * nwv[nf];
          nv[mf][nf][r] = v;
          const int row = wr * 64 + mf * 16 + cr + r;
          const int col = wc * 64 + nf * 16 + fr;
          const bf16 hv = __float2bfloat16(v);
          unsigned short ub;
          __builtin_memcpy(&ub, &hv, 2);
          T16[row * 136 + col] = ub;
        }
    __syncthreads();

    // 3) RoPE (partner from T16, own value fp32) -> fp16 bits back into T16
    unsigned short ofp[4][4][4];
#pragma unroll
    for (int mf = 0; mf < 4; ++mf)
#pragma unroll
      for (int nf = 0; nf < 4; ++nf)
#pragma unroll
        for (int r = 0; r < 4; ++r) {
          const int row = wr * 64 + mf * 16 + cr + r;
          const int col = wc * 64 + nf * 16 + fr;
          const long srow = row0 + row;
          unsigned short pb = T16[row * 136 + (col ^ 64)];
          bf16 pbh;
          __builtin_memcpy(&pbh, &pb, 2);
          const float nvp = __bfloat162float(pbh);
          const float c = cosb[srow * HD + col];
          const float s = sinb[srow * HD + col];
          const float ov = (wc == 0) ? (nv[mf][nf][r] * c - nvp * s)
                                     : (nv[mf][nf][r] * c + nvp * s);
          const _Float16 oh = (_Float16)(ov * scale);
          unsigned short ob;
          __builtin_memcpy(&ob, &oh, 2);
          ofp[mf][nf][r] = ob;
        }
    __syncthreads();   // all partner reads done -> safe to overwrite
#pragma unroll
    for (int mf = 0; mf < 4; ++mf)
#pragma unroll
      for (int nf = 0; nf < 4; ++nf)
#pragma unroll
        for (int r = 0; r < 4; ++r) {
          const int row = wr * 64 + mf * 16 + cr + r;
          const int col = wc * 64 + nf * 16 + fr;
          T16[row * 136 + col] = ofp[mf][nf][r];
        }
    __syncthreads();

    // 4) vectorized fp16 stores (row-threads)
    _Float16* dst = (slot < 32) ? qf : kf;
    const int hidx = (slot < 32) ? slot : (slot - 32);
    const int rrow = w * 32 + (lane & 31);
    const int hi2 = lane >> 5;
    const long base = ((long)hidx * SLEN + row0 + rrow) * HD;
#pragma unroll
    for (int jv = 0; jv < 8; ++jv) {
      const f16x8 o8 = *(const f16x8*)((const _Float16*)T16 + rrow * 136 + hi2 * 64 + jv * 8);
      *(f16x8*)(dst + base + hi2 * 64 + jv * 8) = o8;
    }
  } else {
    // V: acc -> bf16 T16 -> transposed Vt[d][s]
#pragma unroll
    for (int mf = 0; mf < 4; ++mf)
#pragma unroll
      for (int nf = 0; nf < 4; ++nf)
#pragma unroll
        for (int r = 0; r < 4; ++r) {
          const int row = wr * 64 + mf * 16 + cr + r;
          const int col = wc * 64 + nf * 16 + fr;
          const bf16 hv = __float2bfloat16(acc[mf][nf][r]);
          unsigned short ub;
          __builtin_memcpy(&ub, &hv, 2);
          T16[row * 136 + col] = ub;
        }
    __syncthreads();
    const int kvh = slot - 40;
    const int d = w * 32 + (lane >> 1);
    const int sh = lane & 1;
    const long vb = (long)kvh * HD * SLEN + (long)d * SLEN + row0 + sh * 64;
#pragma unroll
    for (int jv = 0; jv < 8; ++jv) {
      short8 o8;
#pragma unroll
      for (int e = 0; e < 8; ++e)
        o8[e] = (short)T16[(sh * 64 + jv * 8 + e) * 136 + d];
      *(short8*)(Vt + vb + jv * 8) = o8;
    }
  }
}

// dst[z][n][k] = bf16(src[z][k][n]), fp32 src. 64x64 tiles via LDS, 4B stores.
__global__ __launch_bounds__(256) void transpose_kernel(
    const float* __restrict__ src, long srcZ, int srcLd,
    bf16* __restrict__ dst, long dstZ, int dstLd)
{
  __shared__ float t[64][65];
  const int z = blockIdx.z;
  src += (long)z * srcZ;
  const long db = (long)z * dstZ;
  const int k0 = blockIdx.x * 64;
  const int n0 = blockIdx.y * 64;
  const int tx = threadIdx.x & 63;
  const int ty = threadIdx.x >> 6;
#pragma unroll
  for (int r = ty; r < 64; r += 4)
    t[r][tx] = src[(long)(k0 + r) * srcLd + n0 + tx];
  __syncthreads();
  const int tx2 = threadIdx.x & 31;
  const int ty2 = threadIdx.x >> 5;
#pragma unroll
  for (int r = ty2; r < 64; r += 8) {
    const unsigned int pr = cvtpk(t[2 * tx2][r], t[2 * tx2 + 1][r]);
    *(unsigned int*)(dst + db + (long)(n0 + r) * dstLd + k0 + 2 * tx2) = pr;
  }
}

__global__ __launch_bounds__(256) void cvt_bf16_kernel(
    const float* __restrict__ x, bf16* __restrict__ y, int n)
{
  const int i = (blockIdx.x * 256 + threadIdx.x) * 4;
  if (i >= n) return;
  const f32x4 v = *(const f32x4*)(x + i);
#pragma unroll
  for (int j = 0; j < 4; ++j) y[i + j] = __float2bfloat16(v[j]);
}

// Flash v7 (round-15 proven): NO-max unnormalized softmax; P = 2^s (Q carries
// log2e); row sums via ones-MFMA into o4. 4 waves x 32 q-rows; 512 blocks, 2/CU.
__global__ __launch_bounds__(256, 2) void flash_kernel(
    const _Float16* __restrict__ qf, const _Float16* __restrict__ kf,
    const bf16* __restrict__ vt,   // [kvh][d=128][s=2048]
    bf16* __restrict__ AO)         // [2048][4096]
{
  __shared__ __align__(16) _Float16 sK[2][64 * 128];
  __shared__ __align__(16) bf16 sV[2][64 * 128];

  const int lin = blockIdx.x;
  const int swz = (lin & 7) * 64 + (lin >> 3);
  const int head = swz >> 4;
  const int qt = swz & 15;
  const int kvh = head >> 2;

  const int tid = threadIdx.x;
  const int w = tid >> 6;
  const int lane = tid & 63;
  const int q31 = lane & 31;
  const int hi = lane >> 5;

  f16x8 bq[8];
  {
    const long qb = ((long)head * SLEN + qt * 128 + w * 32 + q31) * HD + hi * 8;
#pragma unroll
    for (int ks = 0; ks < 8; ++ks)
      bq[ks] = *(const f16x8*)(qf + qb + ks * 16);
  }

  short8 ones;
#pragma unroll
  for (int e = 0; e < 8; ++e) ones[e] = (short)0x3F80;  // bf16 1.0

  const _Float16* kb = kf + (long)kvh * SLEN * HD;
  const bf16* vb = vt + (long)kvh * HD * SLEN;

  auto stage = [&](int t, int buf) {
#pragma unroll
    for (int i = 0; i < 4; ++i) {
      const int c = i * 256 + tid;
      const int row = c >> 4;
      const int sg = (c & 15) ^ (row & 15);
      gld16(kb + (long)(t * 64 + row) * HD + sg * 8,
            (_Float16*)sK[buf] + (i * 256 + w * 64) * 8);
    }
#pragma unroll
    for (int i = 0; i < 4; ++i) {
      const int c = i * 256 + tid;
      const int rp = c >> 4;
      const int sg = (c & 15) ^ (rp & 15);
      const int d = rp * 2 + (sg >> 3);
      gld16(vb + (long)d * SLEN + t * 64 + (sg & 7) * 8,
            (bf16*)sV[buf] + (i * 256 + w * 64) * 8);
    }
  };

  f32x16 o[4] = {};
  f32x16 o4 = {};

  stage(0, 0);
  stage(1, 1);
  asm volatile("s_waitcnt vmcnt(8)" ::: "memory");
  __builtin_amdgcn_sched_barrier(0);
  __builtin_amdgcn_s_barrier();
  __builtin_amdgcn_sched_barrier(0);

  for (int t = 0; t < SLEN / 64; ++t) {
    const int cur = t & 1;
    const _Float16* K = sK[cur];
    const bf16* V = sV[cur];

    f32x16 s0 = {}, s1 = {};
    __builtin_amdgcn_s_setprio(1);
#pragma unroll
    for (int ks = 0; ks < 8; ++ks) {
      const int slot = (2 * ks + hi) ^ (q31 & 15);
      const f16x8 a0 = *(const f16x8*)(K + q31 * 128 + slot * 8);
      const f16x8 a1 = *(const f16x8*)(K + (32 + q31) * 128 + slot * 8);
      s0 = __builtin_amdgcn_mfma_f32_32x32x16_f16(a0, bq[ks], s0, 0, 0, 0);
      s1 = __builtin_amdgcn_mfma_f32_32x32x16_f16(a1, bq[ks], s1, 0, 0, 0);
    }
    __builtin_amdgcn_s_setprio(0);

#pragma unroll
    for (int r = 0; r < 16; ++r) s0[r] = exp2f(s0[r]);
#pragma unroll
    for (int r = 0; r < 16; ++r) s1[r] = exp2f(s1[r]);

    unsigned int pk[16], sw[16];
#pragma unroll
    for (int i = 0; i < 8; ++i) pk[i] = cvtpk(s0[2 * i], s0[2 * i + 1]);
#pragma unroll
    for (int i = 0; i < 8; ++i) pk[8 + i] = cvtpk(s1[2 * i], s1[2 * i + 1]);
#pragma unroll
    for (int i = 0; i < 16; ++i) sw[i] = __shfl_xor((int)pk[i], 32);

    short8 pa[4];
#pragma unroll
    for (int ks = 0; ks < 4; ++ks) {
      const int base = (ks >> 1) * 8 + (ks & 1) * 4 + 2 * hi;
      union { unsigned int u[4]; short8 v; } tu;
      if (hi == 0) {
        tu.u[0] = pk[base]; tu.u[1] = pk[base + 1];
        tu.u[2] = sw[base]; tu.u[3] = sw[base + 1];
      } else {
        tu.u[0] = sw[base]; tu.u[1] = sw[base + 1];
        tu.u[2] = pk[base]; tu.u[3] = pk[base + 1];
      }
      pa[ks] = tu.v;
    }

    __builtin_amdgcn_s_setprio(1);
#pragma unroll
    for (int ks = 0; ks < 4; ++ks)
      o4 = __builtin_amdgcn_mfma_f32_32x32x16_bf16(pa[ks], ones, o4, 0, 0, 0);
#pragma unroll
    for (int nt = 0; nt < 4; ++nt) {
      const int d = nt * 32 + q31;
      const int rp = d >> 1;
      const int sbase = ((d & 1) << 3) + hi;
#pragma unroll
      for (int ks = 0; ks < 4; ++ks) {
        const int slot = (sbase + 2 * ks) ^ (rp & 15);
        const short8 bv = *(const short8*)(V + rp * 128 + slot * 8);
        o[nt] = __builtin_amdgcn_mfma_f32_32x32x16_bf16(pa[ks], bv, o[nt], 0, 0, 0);
      }
    }
    __builtin_amdgcn_s_setprio(0);

    __builtin_amdgcn_s_barrier();
    __builtin_amdgcn_sched_barrier(0);
    if (t + 2 < SLEN / 64) {
      stage(t + 2, cur);
      asm volatile("s_waitcnt vmcnt(8)" ::: "memory");
    } else {
      asm volatile("s_waitcnt vmcnt(0)" ::: "memory");
    }
    __builtin_amdgcn_sched_barrier(0);
    __builtin_amdgcn_s_barrier();
    __builtin_amdgcn_sched_barrier(0);
  }

  f32x16 inv;
#pragma unroll
  for (int r = 0; r < 16; ++r) inv[r] = 1.0f / o4[r];
#pragma unroll
  for (int nt = 0; nt < 4; ++nt)
#pragma unroll
    for (int rr = 0; rr < 4; ++rr)
#pragma unroll
      for (int j = 0; j < 4; ++j) {
        const long row = qt * 128 + w * 32 + 8 * rr + 4 * hi + j;
        AO[row * HIDN + head * 128 + nt * 32 + q31] =
            __float2bfloat16(o[nt][rr * 4 + j] * inv[rr * 4 + j]);
      }
}

extern "C" void kernel_launch(void* const* d_in, const int* in_sizes, int n_in,
                              void* d_out, int out_size, void* d_ws, size_t ws_size,
                              hipStream_t stream)
{
  const float* hs   = (const float*)d_in[0];
  const float* cosb = (const float*)d_in[1];
  const float* sinb = (const float*)d_in[2];
  const float* wq   = (const float*)d_in[3];
  const float* wk   = (const float*)d_in[4];
  const float* wv   = (const float*)d_in[5];
  const float* wo   = (const float*)d_in[6];
  const float* qw   = (const float*)d_in[7];
  const float* kw   = (const float*)d_in[8];
  const float* eps  = (const float*)d_in[9];

  const size_t MB = 1024 * 1024;
  if (ws_size < 116 * MB) return;  // known-good budget
  uint8_t* ws = (uint8_t*)d_ws;

  bf16*  hsb = (bf16*)(ws + 0 * MB);         // [2048][4096]       16 MiB
  bf16*  WT  = (bf16*)(ws + 16 * MB);        // [6144][4096]       48 MiB
  _Float16* qf = (_Float16*)(ws + 64 * MB);  // [32][2048][128]    16 MiB
  _Float16* kf = (_Float16*)(ws + 80 * MB);  // [8][2048][128]      4 MiB
  bf16*  Vt  = (bf16*)(ws + 84 * MB);        // [8][128][2048]      4 MiB
  bf16*  AO  = (bf16*)(ws + 88 * MB);        // [2048][4096]       16 MiB
  bf16*  WoT = (bf16*)(ws + 0 * MB);         // [4096][4096]       32 MiB (over hsb/WT)

  cvt_bf16_kernel<<<SLEN * HIDN / 4 / 256, 256, 0, stream>>>(hs, hsb, SLEN * HIDN);

  transpose_kernel<<<dim3(64, 64, 1), 256, 0, stream>>>(wq, 0, HIDN, WT, 0, HIDN);
  transpose_kernel<<<dim3(64, 16, 1), 256, 0, stream>>>(wk, 0, 1024, WT + (size_t)4096 * HIDN, 0, HIDN);
  transpose_kernel<<<dim3(64, 16, 1), 256, 0, stream>>>(wv, 0, 1024, WT + (size_t)5120 * HIDN, 0, HIDN);

  gemm_qkv_kernel<<<dim3(48, 16, 1), 256, 0, stream>>>(
      hsb, WT, qf, kf, Vt, cosb, sinb, qw, kw, eps, HIDN, HIDN, HIDN);

  transpose_kernel<<<dim3(64, 64, 1), 256, 0, stream>>>(wo, 0, HIDN, WoT, 0, HIDN);

  flash_kernel<<<dim3(512, 1, 1), 256, 0, stream>>>(qf, kf, Vt, AO);

  gemm_pipe_kernel<<<dim3(32, 16, 1), 256, 0, stream>>>(AO, WoT, (float*)d_out, HIDN, HIDN, HIDN, HIDN);
}